// Round 1
// baseline (97.847 us; speedup 1.0000x reference)
//
#include <hip/hip_runtime.h>
#include <math.h>

#define TPB 256
#define ICHUNK 256
#define EPSF 1e-15f

// Pack per-i data: x = R/h, y = delta, z = L = exp(g2-g1), w = unused.
__global__ void setup_kernel(const float* __restrict__ m_z, const float* __restrict__ y,
                             const float* __restrict__ delta, float4* __restrict__ rdl,
                             float* __restrict__ A, float* __restrict__ B,
                             float* __restrict__ out, float inv_h, int n) {
    int i = blockIdx.x * TPB + threadIdx.x;
    if (i < n) {
        float g1 = m_z[2 * i];
        float g2 = m_z[2 * i + 1];
        float R = g1 + __logf(y[i]);
        rdl[i] = make_float4(R * inv_h, delta[i], __expf(g2 - g1), 0.0f);
        A[i] = 0.0f;
        B[i] = 0.0f;
    }
    if (i == 0) out[0] = 0.0f;  // harness poisons d_out to 0xAA
}

// Main O(n^2) kernel: each thread owns column j; iterate an i-tile staged in LDS.
// A[j] += sum_i d_i * exp(-0.5*dr^2);  B[j] += sum_i L_i * Phi(dr);  dr = (R_i-R_j)/h.
// Phi via A&S 7.1.26 erf approx, reusing the SAME exp(-dr^2/2) (z = |dr|/sqrt2 -> z^2 = dr^2/2).
__global__ __launch_bounds__(TPB) void pair_kernel(const float4* __restrict__ rdl,
                                                   float* __restrict__ A,
                                                   float* __restrict__ B) {
    __shared__ float4 tile[ICHUNK];
    const int j = blockIdx.x * TPB + threadIdx.x;
    const float Rj = rdl[j].x;  // pre-scaled R/h
    const int i0 = blockIdx.y * ICHUNK;
    for (int k = threadIdx.x; k < ICHUNK; k += TPB) tile[k] = rdl[i0 + k];
    __syncthreads();

    float accA = 0.0f, accB = 0.0f;
#pragma unroll 8
    for (int k = 0; k < ICHUNK; ++k) {
        float4 v = tile[k];            // broadcast LDS read (conflict-free)
        float dr = v.x - Rj;           // (R_i - R_j)/h
        float e = __expf(-0.5f * dr * dr);            // one v_exp_f32
        float z = fabsf(dr) * 0.70710678118654752f;   // |dr|/sqrt2
        float t = __builtin_amdgcn_rcpf(fmaf(0.3275911f, z, 1.0f));  // one v_rcp_f32
        float p = fmaf(fmaf(fmaf(fmaf(1.061405429f, t, -1.453152027f), t,
                                 1.421413741f), t, -0.284496736f), t, 0.254829592f) * t;
        float s = copysignf(0.5f, dr);
        float phi = (0.5f + s) - s * (p * e);         // Phi(dr), abs err ~1.5e-7
        accA = fmaf(v.y, e, accA);
        accB = fmaf(v.z, phi, accB);
    }
    atomicAdd(&A[j], accA);
    atomicAdd(&B[j], accB);
}

// out = (1/n) * sum_j d_j * (R_j - g2_j - log(c1*A_j + eps) + log(B_j/n + eps))
// where c1 = INV_SQRT_2PI/(n*h). This folds S1..S4 of the reference.
__global__ void finalize_kernel(const float* __restrict__ A, const float* __restrict__ B,
                                const float* __restrict__ m_z, const float* __restrict__ y,
                                const float* __restrict__ delta, float* __restrict__ out,
                                float c1, float invn) {
    int j = blockIdx.x * TPB + threadIdx.x;
    float d = delta[j];
    float g1 = m_z[2 * j];
    float g2 = m_z[2 * j + 1];
    float R = g1 + __logf(y[j]);
    float term = d * (R - g2 - __logf(fmaf(c1, A[j], EPSF))
                            + __logf(fmaf(invn, B[j], EPSF)));
    // wave64 shuffle reduce
    for (int o = 32; o > 0; o >>= 1) term += __shfl_down(term, o, 64);
    __shared__ float wsum[TPB / 64];
    if ((threadIdx.x & 63) == 0) wsum[threadIdx.x >> 6] = term;
    __syncthreads();
    if (threadIdx.x == 0) {
        float ssum = 0.0f;
        for (int w = 0; w < TPB / 64; ++w) ssum += wsum[w];
        atomicAdd(out, ssum * invn);
    }
}

extern "C" void kernel_launch(void* const* d_in, const int* in_sizes, int n_in,
                              void* d_out, int out_size, void* d_ws, size_t ws_size,
                              hipStream_t stream) {
    const float* m_z   = (const float*)d_in[0];   // (n,2)
    const float* y     = (const float*)d_in[1];   // (n,1)
    const float* delta = (const float*)d_in[2];   // (n,1)
    float* out = (float*)d_out;
    const int n = in_sizes[1];                    // 8192

    char* ws = (char*)d_ws;
    float4* rdl = (float4*)ws;                          // n * 16 B
    float* A = (float*)(ws + (size_t)n * sizeof(float4));  // n * 4 B
    float* B = A + n;                                      // n * 4 B

    double h = 1.3 * pow((double)n, -0.2);
    float inv_h = (float)(1.0 / h);
    float c1 = (float)(0.3989422804014327 / ((double)n * h));  // INV_SQRT_2PI/(n*h)
    float invn = 1.0f / (float)n;

    int nblk = (n + TPB - 1) / TPB;  // 32
    setup_kernel<<<nblk, TPB, 0, stream>>>(m_z, y, delta, rdl, A, B, out, inv_h, n);
    dim3 grid(nblk, n / ICHUNK);     // 32 x 32 = 1024 blocks
    pair_kernel<<<grid, TPB, 0, stream>>>(rdl, A, B);
    finalize_kernel<<<nblk, TPB, 0, stream>>>(A, B, m_z, y, delta, out, c1, invn);
}